// Round 17
// baseline (33.838 us; speedup 1.0000x reference)
//
#include <hip/hip_runtime.h>

// attention_pooling: out[b,:] = softmax(feats@Wi over valid rows)-weighted
// mean of feats, then @Wj + bj.  softmax weights sum to 1, so
// out = (Σ_n w_n feats_n / Σ_n w_n) @ Wj + bj — no B×N×D×HID GEMM needed.
//
// R17: SOUND fusion. R10/R14/R16 proved the relaxed flag+data protocol has
// an inherent cross-XCD visibility skew (flag can reach the coherence point
// before earlier write-through data stores). Replaced with:
//  - producers accumulate via RETURNING device-scope atomicAdd (RMW executes
//    at the MALL/coherence point; the returned old value keeps the sc0 form
//    and makes vmcnt-ack mean "executed", not "posted"). No copies of acc
//    lines can exist anywhere -> no staleness hazard, by construction.
//  - __syncthreads() (per-wave vmcnt(0)) -> all adds executed -> ONE
//    atomicAdd(&done[b],1); the block seeing nch-1 finishes graph b inline
//    (read acc with agent-scope atomic loads, divide, Wj GEMM). No flags,
//    no polling, no fences, no consumer blocks, no cross-call ws state.
//  - 66KB memsetAsync per call clears done+acc (R1/R8 precedent: cheap).
//  - R4: __threadfence banned. R8: ticket-cursor banned. R5: no launch cap.
//  - fp32 atomic order varies per call (~1e-6 noise): R1 passed the
//    tripwire with this exact pattern; final threshold is 1.66e-2.

#define NDIM 256        // NODE_DIM + HID_DIM
#define HID 128
#define NMAX 4096
#define ROWS_PER_BLK 160
#define NCHUNK 26                      // ceil(4096/160)
#define ASTRIDE 257                    // 256 acc + 1 lsum
#define ALOAD(p) __hip_atomic_load((p), __ATOMIC_RELAXED, __HIP_MEMORY_SCOPE_AGENT)

__global__ __launch_bounds__(512) void pool_fused(
    const float* __restrict__ feats, const int* __restrict__ counts,
    const float* __restrict__ Wi, const float* __restrict__ bi,
    const float* __restrict__ Wj, const float* __restrict__ bj,
    unsigned int* __restrict__ done, float* __restrict__ acc_g,
    float* __restrict__ out)
{
    const int b     = blockIdx.y;
    const int count = counts[b];
    const int tid   = threadIdx.x;
    const int nch   = (count + ROWS_PER_BLK - 1) / ROWS_PER_BLK;

    const int row0 = blockIdx.x * ROWS_PER_BLK;
    if (row0 >= count) return;                    // masked chunk: never read
    const int row_end = min(row0 + ROWS_PER_BLK, count);

    __shared__ float lds_acc[8][NDIM];
    __shared__ float lds_l[8];
    __shared__ float pooled[NDIM];
    __shared__ float tmp[4][HID];
    __shared__ unsigned int s_old;

    // ---------------- producer: one 160-row chunk ----------------
    const int lane = tid & 63;
    const int wv   = tid >> 6;       // 0..7
    const int g    = lane >> 4;      // 0..3: row within quad
    const int q    = lane & 15;      // col-group owner

    const float4* Wi4 = reinterpret_cast<const float4*>(Wi);
    const float4 wi0 = Wi4[q], wi1 = Wi4[16 + q], wi2 = Wi4[32 + q], wi3 = Wi4[48 + q];
    const float  fbi = bi[0];

    const float* fb = feats + (size_t)b * NMAX * NDIM;

    float4 a0 = {0,0,0,0}, a1 = {0,0,0,0}, a2 = {0,0,0,0}, a3 = {0,0,0,0};
    float lsum = 0.f;

    const int wbase = row0 + wv * 20;             // wave owns 20 rows
    #pragma unroll
    for (int it = 0; it < 5; ++it) {
        const int r = wbase + it * 4 + g;
        const bool valid = (r < row_end);
        float4 f0 = {0,0,0,0}, f1 = {0,0,0,0}, f2 = {0,0,0,0}, f3 = {0,0,0,0};
        if (valid) {
            const float4* rp = reinterpret_cast<const float4*>(fb + (size_t)r * NDIM);
            f0 = rp[q]; f1 = rp[16 + q]; f2 = rp[32 + q]; f3 = rp[48 + q];
        }
        float sp = f0.x*wi0.x + f0.y*wi0.y + f0.z*wi0.z + f0.w*wi0.w
                 + f1.x*wi1.x + f1.y*wi1.y + f1.z*wi1.z + f1.w*wi1.w
                 + f2.x*wi2.x + f2.y*wi2.y + f2.z*wi2.z + f2.w*wi2.w
                 + f3.x*wi3.x + f3.y*wi3.y + f3.z*wi3.z + f3.w*wi3.w;
        sp += __shfl_xor(sp, 1, 64);
        sp += __shfl_xor(sp, 2, 64);
        sp += __shfl_xor(sp, 4, 64);
        sp += __shfl_xor(sp, 8, 64);
        const float w = valid ? __expf(sp + fbi) : 0.f;
        lsum += w;
        a0.x += w*f0.x; a0.y += w*f0.y; a0.z += w*f0.z; a0.w += w*f0.w;
        a1.x += w*f1.x; a1.y += w*f1.y; a1.z += w*f1.z; a1.w += w*f1.w;
        a2.x += w*f2.x; a2.y += w*f2.y; a2.z += w*f2.z; a2.w += w*f2.w;
        a3.x += w*f3.x; a3.y += w*f3.y; a3.z += w*f3.z; a3.w += w*f3.w;
    }

    #define COMB(x) x += __shfl_xor(x, 16, 64); x += __shfl_xor(x, 32, 64)
    COMB(a0.x); COMB(a0.y); COMB(a0.z); COMB(a0.w);
    COMB(a1.x); COMB(a1.y); COMB(a1.z); COMB(a1.w);
    COMB(a2.x); COMB(a2.y); COMB(a2.z); COMB(a2.w);
    COMB(a3.x); COMB(a3.y); COMB(a3.z); COMB(a3.w);
    COMB(lsum);
    #undef COMB

    if (g == 0) {                                 // lane < 16: one writer per col-set
        float* dst = &lds_acc[wv][0];
        *reinterpret_cast<float4*>(&dst[q*4      ]) = a0;
        *reinterpret_cast<float4*>(&dst[q*4 +  64]) = a1;
        *reinterpret_cast<float4*>(&dst[q*4 + 128]) = a2;
        *reinterpret_cast<float4*>(&dst[q*4 + 192]) = a3;
        if (q == 0) lds_l[wv] = lsum;
    }
    __syncthreads();

    // accumulate into the per-graph global accumulator: RETURNING atomicAdd
    // (device scope -> executes at the coherence point; kept-live return
    // forces the sc0 form so vmcnt ack == executed, not posted).
    float* acc = acc_g + (size_t)b * ASTRIDE;
    if (tid < NDIM) {
        float v = 0.f;
        #pragma unroll
        for (int k = 0; k < 8; ++k) v += lds_acc[k][tid];
        float old = atomicAdd(&acc[tid], v);
        asm volatile("" :: "v"(old));
    } else if (tid == NDIM) {
        float lv = 0.f;
        #pragma unroll
        for (int k = 0; k < 8; ++k) lv += lds_l[k];
        float old = atomicAdd(&acc[NDIM], lv);
        asm volatile("" :: "v"(old));
    }
    __syncthreads();   // per-wave vmcnt(0): every add has EXECUTED at MALL

    if (tid == 0) s_old = atomicAdd(&done[b], 1u);
    __syncthreads();
    if (s_old != (unsigned int)(nch - 1)) return;

    // ---------------- finisher: last block for graph b (inline) ----------------
    // acc values are authoritative at the coherence point (written by RMWs;
    // no cached copies exist); read with agent-scope atomic loads.
    {
        const float lv = ALOAD(&acc[NDIM]);       // broadcast address
        if (tid < NDIM) {
            const float av = ALOAD(&acc[tid]);
            pooled[tid] = av / lv;
        }
    }
    __syncthreads();

    const int j  = tid & (HID - 1);
    const int ks = (tid >> 7) * 64;               // K-quarter
    float s = 0.f;
    #pragma unroll 16
    for (int k = 0; k < 64; ++k)
        s += pooled[ks + k] * Wj[(ks + k) * HID + j];   // Wj coalesced over j
    tmp[tid >> 7][j] = s;
    __syncthreads();
    if (tid < HID)
        out[b * HID + tid] = tmp[0][tid] + tmp[1][tid] + tmp[2][tid]
                           + tmp[3][tid] + bj[tid];
}

extern "C" void kernel_launch(void* const* d_in, const int* in_sizes, int n_in,
                              void* d_out, int out_size, void* d_ws, size_t ws_size,
                              hipStream_t stream) {
    const float* feats  = (const float*)d_in[0];
    const int*   counts = (const int*)  d_in[1];
    const float* Wi     = (const float*)d_in[2];
    const float* bi     = (const float*)d_in[3];
    const float* Wj     = (const float*)d_in[4];
    const float* bj     = (const float*)d_in[5];
    float* out = (float*)d_out;

    const int B = in_sizes[1];                    // 64

    unsigned int* done  = (unsigned int*)d_ws;                // [64]   @ 0
    float*        acc_g = (float*)((char*)d_ws + 256);        // [64][257]

    hipMemsetAsync(d_ws, 0, 256 + (size_t)B * ASTRIDE * sizeof(float), stream);

    dim3 g1(NCHUNK, B);
    pool_fused<<<g1, 512, 0, stream>>>(feats, counts, Wi, bi, Wj, bj,
                                       done, acc_g, out);
}

// Round 20
// 28.836 us; speedup vs baseline: 1.1735x; 1.1735x over previous
//
#include <hip/hip_runtime.h>

// attention_pooling: out[b,:] = softmax(feats@Wi over valid rows)-weighted
// mean of feats, then @Wj + bj.  softmax weights sum to 1, so
// out = (Σ_n w_n feats_n / Σ_n w_n) @ Wj + bj — no B×N×D×HID GEMM needed.
//
// R20: SOUND flag protocol + one-round tail (fastest sound design).
//  - R10/R16 root cause: non-returning store vmcnt-ack = POSTED, not
//    EXECUTED — a later flag could reach the coherence point before the
//    data. Fix: producers commit partials with RETURNING atomicExch into
//    PRIVATE per-chunk buffers (return originates at the MALL -> ack =
//    executed; R17 validated returning-RMW soundness end-to-end). Flag is
//    set only AFTER __syncthreads waits on those returns. Therefore
//    "flag observed => data executed" is sound, and the consumer may read
//    immediately: R16's one-round burst reduce becomes legal.
//  - Consumer: poll all flags lane-parallel; then 26 agent-scope atomic
//    loads (L2-bypass, read the MALL) fully unrolled into named registers
//    (rule-#20-safe), predicated accumulate (c>=nch discarded, reads stay
//    in-slab); self-clear flags (no stale-MAGIC; kernel boundary orders
//    the clear before next call's sets); divide; Wj GEMM.
//  - No memset (exchange overwrites 0xAA poison), no __threadfence (R4),
//    no ticket cursor (R8), no min-waves cap (R5), private partials (no
//    contention, unlike R17's shared-acc adds).

#define NDIM 256        // NODE_DIM + HID_DIM
#define HID 128
#define NMAX 4096
#define ROWS_PER_BLK 160
#define NCHUNK 26                      // ceil(4096/160)
#define PSTRIDE 260                    // 256 acc + 1 lsum, padded
#define FLAG_MAGIC 0x5EED5EEDu
#define CPH 13                         // chunks per half (NCHUNK/2)

#define ALOAD(p)     __hip_atomic_load((p),  __ATOMIC_RELAXED, __HIP_MEMORY_SCOPE_AGENT)
#define ASTOREU(p,v) __hip_atomic_store((p), (v), __ATOMIC_RELAXED, __HIP_MEMORY_SCOPE_AGENT)

__global__ __launch_bounds__(512) void pool_fused(
    const float* __restrict__ feats, const int* __restrict__ counts,
    const float* __restrict__ Wi, const float* __restrict__ bi,
    const float* __restrict__ Wj, const float* __restrict__ bj,
    unsigned int* __restrict__ flags, float* __restrict__ part_g,
    float* __restrict__ out)
{
    const int b     = blockIdx.y;
    const int count = counts[b];
    const int tid   = threadIdx.x;
    const int nch   = (count + ROWS_PER_BLK - 1) / ROWS_PER_BLK;

    __shared__ float lds_acc[8][NDIM];
    __shared__ float lds_l[8];
    __shared__ float red[2][NDIM];
    __shared__ float redl[2];
    __shared__ float pooled[NDIM];
    __shared__ float tmp[4][HID];

    if (blockIdx.x < NCHUNK) {
        // ---------------- producer: one 160-row chunk ----------------
        const int row0 = blockIdx.x * ROWS_PER_BLK;
        if (row0 >= count) return;                    // masked chunk: never read
        const int row_end = min(row0 + ROWS_PER_BLK, count);

        const int lane = tid & 63;
        const int wv   = tid >> 6;       // 0..7
        const int g    = lane >> 4;      // 0..3: row within quad
        const int q    = lane & 15;      // col-group owner

        const float4* Wi4 = reinterpret_cast<const float4*>(Wi);
        const float4 wi0 = Wi4[q], wi1 = Wi4[16 + q], wi2 = Wi4[32 + q], wi3 = Wi4[48 + q];
        const float  fbi = bi[0];

        const float* fb = feats + (size_t)b * NMAX * NDIM;

        float4 a0 = {0,0,0,0}, a1 = {0,0,0,0}, a2 = {0,0,0,0}, a3 = {0,0,0,0};
        float lsum = 0.f;

        const int wbase = row0 + wv * 20;             // wave owns 20 rows
        #pragma unroll
        for (int it = 0; it < 5; ++it) {
            const int r = wbase + it * 4 + g;
            const bool valid = (r < row_end);
            float4 f0 = {0,0,0,0}, f1 = {0,0,0,0}, f2 = {0,0,0,0}, f3 = {0,0,0,0};
            if (valid) {
                const float4* rp = reinterpret_cast<const float4*>(fb + (size_t)r * NDIM);
                f0 = rp[q]; f1 = rp[16 + q]; f2 = rp[32 + q]; f3 = rp[48 + q];
            }
            float sp = f0.x*wi0.x + f0.y*wi0.y + f0.z*wi0.z + f0.w*wi0.w
                     + f1.x*wi1.x + f1.y*wi1.y + f1.z*wi1.z + f1.w*wi1.w
                     + f2.x*wi2.x + f2.y*wi2.y + f2.z*wi2.z + f2.w*wi2.w
                     + f3.x*wi3.x + f3.y*wi3.y + f3.z*wi3.z + f3.w*wi3.w;
            sp += __shfl_xor(sp, 1, 64);
            sp += __shfl_xor(sp, 2, 64);
            sp += __shfl_xor(sp, 4, 64);
            sp += __shfl_xor(sp, 8, 64);
            const float w = valid ? __expf(sp + fbi) : 0.f;
            lsum += w;
            a0.x += w*f0.x; a0.y += w*f0.y; a0.z += w*f0.z; a0.w += w*f0.w;
            a1.x += w*f1.x; a1.y += w*f1.y; a1.z += w*f1.z; a1.w += w*f1.w;
            a2.x += w*f2.x; a2.y += w*f2.y; a2.z += w*f2.z; a2.w += w*f2.w;
            a3.x += w*f3.x; a3.y += w*f3.y; a3.z += w*f3.z; a3.w += w*f3.w;
        }

        #define COMB(x) x += __shfl_xor(x, 16, 64); x += __shfl_xor(x, 32, 64)
        COMB(a0.x); COMB(a0.y); COMB(a0.z); COMB(a0.w);
        COMB(a1.x); COMB(a1.y); COMB(a1.z); COMB(a1.w);
        COMB(a2.x); COMB(a2.y); COMB(a2.z); COMB(a2.w);
        COMB(a3.x); COMB(a3.y); COMB(a3.z); COMB(a3.w);
        COMB(lsum);
        #undef COMB

        if (g == 0) {                                 // lane < 16: one writer per col-set
            float* dst = &lds_acc[wv][0];
            *reinterpret_cast<float4*>(&dst[q*4      ]) = a0;
            *reinterpret_cast<float4*>(&dst[q*4 +  64]) = a1;
            *reinterpret_cast<float4*>(&dst[q*4 + 128]) = a2;
            *reinterpret_cast<float4*>(&dst[q*4 + 192]) = a3;
            if (q == 0) lds_l[wv] = lsum;
        }
        __syncthreads();

        // COMMIT partials: returning atomicExch -> executed at the MALL
        // before the vmcnt ack (overwrites poison; private buffer, no
        // contention). Flag set only after the syncthreads waits on returns.
        float* part = part_g + (size_t)(b * NCHUNK + blockIdx.x) * PSTRIDE;
        if (tid < NDIM) {
            float v = 0.f;
            #pragma unroll
            for (int k = 0; k < 8; ++k) v += lds_acc[k][tid];
            float old = atomicExch(&part[tid], v);
            asm volatile("" :: "v"(old));             // keep returning form live
        } else if (tid == NDIM) {
            float v = 0.f;
            #pragma unroll
            for (int k = 0; k < 8; ++k) v += lds_l[k];
            float old = atomicExch(&part[NDIM], v);
            asm volatile("" :: "v"(old));
        }
        __syncthreads();   // waits vmcnt(0): every exchange has EXECUTED
        if (tid == 0)
            ASTOREU(&flags[b * NCHUNK + blockIdx.x], FLAG_MAGIC);
        return;
    }

    // ---------------- consumer: blockIdx.x == NCHUNK, one per graph ----------------
    // Phase 1: observe ALL flags (lane-parallel). flag => data executed (sound).
    if (tid < 64) {
        for (int c = (int)tid; c < nch; c += 64)
            while (ALOAD(&flags[b * NCHUNK + c]) != FLAG_MAGIC)
                __builtin_amdgcn_s_sleep(2);
    }
    __syncthreads();                  // all 512 threads see: every flag set
    asm volatile("" ::: "memory");    // no hoisting the reduce loads above polls

    // Phase 2: ONE-ROUND burst reduce — 26 agent-scope loads (read the MALL)
    // fully unrolled into named registers, then predicated sum (c >= nch
    // values discarded; reads stay inside the part_g slab).
    const int t    = tid & (NDIM - 1);
    const int half = tid >> 8;                    // 0/1
    float v[CPH], w[CPH];
    {
        const size_t base = (size_t)b * NCHUNK + half;
        #pragma unroll
        for (int i = 0; i < CPH; ++i) {
            const float* p = part_g + (base + 2 * i) * PSTRIDE;
            v[i] = ALOAD(&p[t]);
            w[i] = ALOAD(&p[NDIM]);
        }
    }
    float acc = 0.f, l = 0.f;
    #pragma unroll
    for (int i = 0; i < CPH; ++i) {
        if (half + 2 * i < nch) { acc += v[i]; l += w[i]; }
    }
    red[half][t] = acc;
    if (t == 0) redl[half] = l;
    __syncthreads();                  // all partial reads complete

    // Self-clear this graph's flags: next call's consumers must wait again.
    // Kernel boundary orders these clears before the next call's sets.
    if (tid < nch)
        ASTOREU(&flags[b * NCHUNK + tid], 0u);

    if (tid < NDIM)
        pooled[tid] = (red[0][tid] + red[1][tid]) / (redl[0] + redl[1]);
    __syncthreads();

    const int j  = tid & (HID - 1);
    const int ks = (tid >> 7) * 64;               // K-quarter
    float s = 0.f;
    #pragma unroll 16
    for (int k = 0; k < 64; ++k)
        s += pooled[ks + k] * Wj[(ks + k) * HID + j];   // Wj coalesced over j
    tmp[tid >> 7][j] = s;
    __syncthreads();
    if (tid < HID)
        out[b * HID + tid] = tmp[0][tid] + tmp[1][tid] + tmp[2][tid]
                           + tmp[3][tid] + bj[tid];
}

extern "C" void kernel_launch(void* const* d_in, const int* in_sizes, int n_in,
                              void* d_out, int out_size, void* d_ws, size_t ws_size,
                              hipStream_t stream) {
    const float* feats  = (const float*)d_in[0];
    const int*   counts = (const int*)  d_in[1];
    const float* Wi     = (const float*)d_in[2];
    const float* bi     = (const float*)d_in[3];
    const float* Wj     = (const float*)d_in[4];
    const float* bj     = (const float*)d_in[5];
    float* out = (float*)d_out;

    const int B = in_sizes[1];                    // 64

    unsigned int* flags  = (unsigned int*)d_ws;              // [B*NCHUNK]
    float*        part_g = (float*)((char*)d_ws + 16384);    // [B][NCHUNK][PSTRIDE]

    dim3 g1(NCHUNK + 1, B);
    pool_fused<<<g1, 512, 0, stream>>>(feats, counts, Wi, bi, Wj, bj,
                                       flags, part_g, out);
}